// Round 1
// baseline (1366.448 us; speedup 1.0000x reference)
//
#include <hip/hip_runtime.h>
#include <math.h>

#define THREADS 256

// ---------------------------------------------------------------------------
// Workspace layout (floats):
//   K0: 23*125        = 2875
//   K1: 23*20*125     = 57500
//   K2: 20*20*125     = 50000
//   A0: 16*20*33^3    = 11,499,840
//   A1: 16*20*18^3    = 1,866,240
//   A2: 16*20*10^3    = 320,000
// total ~13.8M floats = ~55 MB
// ---------------------------------------------------------------------------

// Synthesize radial basis B[3][125] and the three conv kernels K = sum_j W*B_j.
__global__ void synth_kernel(const float* __restrict__ W0,
                             const float* __restrict__ W1,
                             const float* __restrict__ W2,
                             float* __restrict__ K0,
                             float* __restrict__ K1,
                             float* __restrict__ K2) {
  __shared__ float Bsh[3][128];
  __shared__ float nrm[3];
  const int t = threadIdx.x;
  if (t < 125) {
    // r depends only on the offset multiset -> decomposition order irrelevant
    float dz = (float)(t / 25) - 2.0f;
    float dy = (float)((t / 5) % 5) - 2.0f;
    float dx = (float)(t % 5) - 2.0f;
    float r = sqrtf(dx * dx + dy * dy + dz * dz);
    for (int j = 0; j < 3; ++j) {
      float d = (r - (float)j) * (1.0f / 0.6f);
      Bsh[j][t] = expf(-0.5f * d * d);
    }
  }
  __syncthreads();
  if (t < 3) {
    float s = 0.f;
    for (int k = 0; k < 125; ++k) s += Bsh[t][k] * Bsh[t][k];
    nrm[t] = rsqrtf(s);
  }
  __syncthreads();
  if (t < 125) {
    for (int j = 0; j < 3; ++j) Bsh[j][t] *= nrm[j];
  }
  __syncthreads();
  for (int i = t; i < 23 * 1 * 125; i += blockDim.x) {
    int k = i % 125, oi = i / 125;
    K0[i] = W0[oi * 3] * Bsh[0][k] + W0[oi * 3 + 1] * Bsh[1][k] + W0[oi * 3 + 2] * Bsh[2][k];
  }
  for (int i = t; i < 23 * 20 * 125; i += blockDim.x) {
    int k = i % 125, oi = i / 125;
    K1[i] = W1[oi * 3] * Bsh[0][k] + W1[oi * 3 + 1] * Bsh[1][k] + W1[oi * 3 + 2] * Bsh[2][k];
  }
  for (int i = t; i < 20 * 20 * 125; i += blockDim.x) {
    int k = i % 125, oi = i / 125;
    K2[i] = W2[oi * 3] * Bsh[0][k] + W2[oi * 3 + 1] * Bsh[1][k] + W2[oi * 3 + 2] * Bsh[2][k];
  }
}

// Direct conv, stride 2, pad 3, kernel 5^3. One block handles a yx-tile of one
// (batch, z_out) slice. Weights for current input channel staged in LDS.
// Gating (capsule relu/sigmoid structure) fused into the epilogue.
template <int IC, int OC, int DIN, int DOUT, bool GATED>
__global__ __launch_bounds__(THREADS)
void conv_kernel(const float* __restrict__ in, const float* __restrict__ K,
                 float* __restrict__ out) {
  constexpr int NVOX = DOUT * DOUT;
  constexpr int NT = (NVOX + THREADS - 1) / THREADS;
  constexpr int OCOUT = GATED ? 20 : OC;
  constexpr int D3 = DOUT * DOUT * DOUT;

  const int bid = blockIdx.x;
  const int tile = bid % NT;
  const int zb = bid / NT;
  const int b = zb / DOUT;
  const int zo = zb % DOUT;
  const int t = threadIdx.x;

  __shared__ float wsh[OC * 125];

  const int vox = tile * THREADS + t;
  const bool active = vox < NVOX;
  const int yo = active ? vox / DOUT : 0;
  const int xo = active ? vox % DOUT : 0;

  float acc[OC];
#pragma unroll
  for (int oc = 0; oc < OC; ++oc) acc[oc] = 0.f;

  for (int ic = 0; ic < IC; ++ic) {
    __syncthreads();
    for (int i = t; i < OC * 125; i += THREADS)
      wsh[i] = K[(i / 125) * (IC * 125) + ic * 125 + (i % 125)];
    __syncthreads();

    const float* __restrict__ ip = in + ((size_t)(b * IC + ic)) * DIN * DIN * DIN;
    for (int kz = 0; kz < 5; ++kz) {
      const int zi = 2 * zo - 3 + kz;
      if (zi < 0 || zi >= DIN) continue;
      for (int ky = 0; ky < 5; ++ky) {
        const int yi = 2 * yo - 3 + ky;
        if (yi < 0 || yi >= DIN) continue;
        const float* __restrict__ row = ip + ((size_t)zi * DIN + yi) * DIN;
        const int kbase = (kz * 5 + ky) * 5;
#pragma unroll
        for (int kx = 0; kx < 5; ++kx) {
          const int xi = 2 * xo - 3 + kx;
          if (xi < 0 || xi >= DIN) continue;
          const float v = row[xi];
#pragma unroll
          for (int oc = 0; oc < OC; ++oc)
            acc[oc] += wsh[oc * 125 + kbase + kx] * v;
        }
      }
    }
  }

  if (active) {
    const size_t spat = ((size_t)zo * DOUT + yo) * DOUT + xo;
    float* __restrict__ op = out + (size_t)b * OCOUT * D3 + spat;
    if (GATED) {
      const float g0 = 1.f / (1.f + expf(-acc[20]));
      const float g1 = 1.f / (1.f + expf(-acc[21]));
      const float g2 = 1.f / (1.f + expf(-acc[22]));
      float o[20];
#pragma unroll
      for (int c = 0; c < 5; ++c) o[c] = fmaxf(acc[c], 0.f);
#pragma unroll
      for (int c = 0; c < 3; ++c) o[5 + c] = acc[5 + c] * g0;
#pragma unroll
      for (int c = 0; c < 5; ++c) o[8 + c] = acc[8 + c] * g1;
#pragma unroll
      for (int c = 0; c < 7; ++c) o[13 + c] = acc[13 + c] * g2;
#pragma unroll
      for (int c = 0; c < 20; ++c) op[(size_t)c * D3] = o[c];
    } else {
#pragma unroll
      for (int c = 0; c < OC; ++c) op[(size_t)c * D3] = acc[c];
    }
  }
}

// AvgSpacial (mean over 1000 voxels) + fc1(relu) + fc2, one block per batch.
__global__ __launch_bounds__(THREADS)
void head_kernel(const float* __restrict__ A2,
                 const float* __restrict__ fc1w, const float* __restrict__ fc1b,
                 const float* __restrict__ fc2w, const float* __restrict__ fc2b,
                 float* __restrict__ out) {
  const int b = blockIdx.x;
  const int t = threadIdx.x;
  __shared__ float part[200];
  __shared__ float xm[20];
  __shared__ float h[50];
  if (t < 200) {
    const int ch = t / 10, seg = t % 10;
    const float* __restrict__ p = A2 + ((size_t)b * 20 + ch) * 1000 + seg * 100;
    float s = 0.f;
    for (int i = 0; i < 100; ++i) s += p[i];
    part[t] = s;
  }
  __syncthreads();
  if (t < 20) {
    float s = 0.f;
    for (int i = 0; i < 10; ++i) s += part[t * 10 + i];
    xm[t] = s * (1.0f / 1000.0f);
  }
  __syncthreads();
  if (t < 50) {
    float s = fc1b[t];
    for (int c = 0; c < 20; ++c) s += xm[c] * fc1w[t * 20 + c];
    h[t] = fmaxf(s, 0.f);
  }
  __syncthreads();
  if (t < 2) {
    float s = fc2b[t];
    for (int k = 0; k < 50; ++k) s += h[k] * fc2w[t * 50 + k];
    out[b * 2 + t] = s;
  }
}

extern "C" void kernel_launch(void* const* d_in, const int* in_sizes, int n_in,
                              void* d_out, int out_size, void* d_ws, size_t ws_size,
                              hipStream_t stream) {
  (void)in_sizes; (void)n_in; (void)out_size; (void)ws_size;
  const float* inp  = (const float*)d_in[0];
  const float* W0   = (const float*)d_in[1];
  const float* W1   = (const float*)d_in[2];
  const float* W2   = (const float*)d_in[3];
  const float* fc1w = (const float*)d_in[4];
  const float* fc1b = (const float*)d_in[5];
  const float* fc2w = (const float*)d_in[6];
  const float* fc2b = (const float*)d_in[7];
  float* out = (float*)d_out;

  float* ws = (float*)d_ws;
  float* K0 = ws;
  float* K1 = K0 + 23 * 125;
  float* K2 = K1 + 23 * 20 * 125;
  float* A0 = K2 + 20 * 20 * 125;
  float* A1 = A0 + (size_t)16 * 20 * 33 * 33 * 33;
  float* A2 = A1 + (size_t)16 * 20 * 18 * 18 * 18;

  hipLaunchKernelGGL(synth_kernel, dim3(1), dim3(256), 0, stream, W0, W1, W2, K0, K1, K2);

  // conv0: [16,1,64^3] -> gated -> [16,20,33^3]; NT=ceil(1089/256)=5
  hipLaunchKernelGGL((conv_kernel<1, 23, 64, 33, true>), dim3(16 * 33 * 5), dim3(THREADS), 0,
                     stream, inp, K0, A0);
  // conv1: [16,20,33^3] -> gated -> [16,20,18^3]; NT=ceil(324/256)=2
  hipLaunchKernelGGL((conv_kernel<20, 23, 33, 18, true>), dim3(16 * 18 * 2), dim3(THREADS), 0,
                     stream, A0, K1, A1);
  // conv2: [16,20,18^3] -> [16,20,10^3]; NT=1
  hipLaunchKernelGGL((conv_kernel<20, 20, 18, 10, false>), dim3(16 * 10 * 1), dim3(THREADS), 0,
                     stream, A1, K2, A2);

  hipLaunchKernelGGL(head_kernel, dim3(16), dim3(THREADS), 0, stream, A2, fc1w, fc1b, fc2w, fc2b,
                     out);
}

// Round 2
// 1045.831 us; speedup vs baseline: 1.3066x; 1.3066x over previous
//
#include <hip/hip_runtime.h>
#include <math.h>

#define THREADS 256
constexpr int BATCH = 16;

// ---------------------------------------------------------------------------
// Workspace layout (floats):
//   K0t [125][23]        : 2875      (tap-major, oc contiguous -> s_load friendly)
//   K1t [20][125][23]    : 57500
//   K2t [20][125][20]    : 50000
//   A0  [16][20][33^3]   : 11,499,840
//   A1  [16][20][18^3]   : 1,866,240
//   X   (variable region): P1 [G1][16][23][18^3], P2 [10][16][20][10^3]
//                           or fallback A2 [16][20][10^3]
// tiers: G1=4 -> 101.0 MB, G1=2 -> 83.9 MB, fallback -> 55.2 MB
// ---------------------------------------------------------------------------

__global__ void synth_kernel(const float* __restrict__ W0,
                             const float* __restrict__ W1,
                             const float* __restrict__ W2,
                             float* __restrict__ K0,
                             float* __restrict__ K1,
                             float* __restrict__ K2) {
  __shared__ float Bsh[3][128];
  __shared__ float nrm[3];
  const int t = threadIdx.x;
  if (t < 125) {
    float dz = (float)(t / 25) - 2.0f;
    float dy = (float)((t / 5) % 5) - 2.0f;
    float dx = (float)(t % 5) - 2.0f;
    float r = sqrtf(dx * dx + dy * dy + dz * dz);
    for (int j = 0; j < 3; ++j) {
      float d = (r - (float)j) * (1.0f / 0.6f);
      Bsh[j][t] = expf(-0.5f * d * d);
    }
  }
  __syncthreads();
  if (t < 3) {
    float s = 0.f;
    for (int k = 0; k < 125; ++k) s += Bsh[t][k] * Bsh[t][k];
    nrm[t] = rsqrtf(s);
  }
  __syncthreads();
  if (t < 125) {
    for (int j = 0; j < 3; ++j) Bsh[j][t] *= nrm[j];
  }
  __syncthreads();
  // K0t[k][oc]
  for (int i = t; i < 125 * 23; i += blockDim.x) {
    int k = i / 23, oc = i % 23;
    const float* w = W0 + oc * 3;
    K0[i] = w[0] * Bsh[0][k] + w[1] * Bsh[1][k] + w[2] * Bsh[2][k];
  }
  // K1t[ic][k][oc], W1 is [23][20][3]
  for (int i = t; i < 20 * 125 * 23; i += blockDim.x) {
    int oc = i % 23, k = (i / 23) % 125, ic = i / (23 * 125);
    const float* w = W1 + (oc * 20 + ic) * 3;
    K1[i] = w[0] * Bsh[0][k] + w[1] * Bsh[1][k] + w[2] * Bsh[2][k];
  }
  // K2t[ic][k][oc], W2 is [20][20][3]
  for (int i = t; i < 20 * 125 * 20; i += blockDim.x) {
    int oc = i % 20, k = (i / 20) % 125, ic = i / (20 * 125);
    const float* w = W2 + (oc * 20 + ic) * 3;
    K2[i] = w[0] * Bsh[0][k] + w[1] * Bsh[1][k] + w[2] * Bsh[2][k];
  }
}

// Direct conv, stride 2, pad 3, 5^3 taps. One thread = one output voxel of one
// ic-group. Weights read with wave-uniform indices (-> scalar loads, FMA with
// SGPR operand). Branch-free boundary handling via clamp + mask.
// EPI: 0 = write partials [g][b][OC][vox], 1 = gated epilogue (G==1, OC==23),
//      2 = plain full write (G==1).
template <int ICTOT, int ICG, int OC, int DIN, int DOUT, int EPI>
__global__ __launch_bounds__(THREADS)
void conv_kernel(const float* __restrict__ in, const float* __restrict__ K,
                 float* __restrict__ out) {
  constexpr int NVOX = DOUT * DOUT * DOUT;
  constexpr int G = ICTOT / ICG;
  constexpr int DIN3 = DIN * DIN * DIN;

  const int tid = blockIdx.x * THREADS + threadIdx.x;
  if (tid >= BATCH * G * NVOX) return;
  const int vox = tid % NVOX;
  const int rest = tid / NVOX;
  const int g = rest % G;
  const int b = rest / G;
  const int zo = vox / (DOUT * DOUT);
  const int yo = (vox / DOUT) % DOUT;
  const int xo = vox % DOUT;

  float acc[OC];
#pragma unroll
  for (int oc = 0; oc < OC; ++oc) acc[oc] = 0.f;

  const float* __restrict__ ip = in + (size_t)(b * ICTOT + g * ICG) * DIN3;
  const float* __restrict__ wp = K + (size_t)(g * ICG) * 125 * OC;

  for (int icl = 0; icl < ICG; ++icl) {
    const float* __restrict__ ipc = ip + (size_t)icl * DIN3;
    const float* __restrict__ wpc = wp + icl * 125 * OC;
    for (int kz = 0; kz < 5; ++kz) {
      const int zi = 2 * zo - 3 + kz;
      const bool zok = (unsigned)zi < (unsigned)DIN;
      const int zic = min(max(zi, 0), DIN - 1);
      for (int ky = 0; ky < 5; ++ky) {
        const int yi = 2 * yo - 3 + ky;
        const bool yzok = zok && ((unsigned)yi < (unsigned)DIN);
        const int yic = min(max(yi, 0), DIN - 1);
        const float* __restrict__ row = ipc + ((size_t)zic * DIN + yic) * DIN;
        const float* __restrict__ wrow = wpc + ((kz * 5 + ky) * 5) * OC;  // uniform
        float v[5];
#pragma unroll
        for (int kx = 0; kx < 5; ++kx) {
          const int xi = 2 * xo - 3 + kx;
          const bool ok = yzok && ((unsigned)xi < (unsigned)DIN);
          const int xic = min(max(xi, 0), DIN - 1);
          const float val = row[xic];
          v[kx] = ok ? val : 0.f;
        }
#pragma unroll
        for (int kx = 0; kx < 5; ++kx) {
#pragma unroll
          for (int oc = 0; oc < OC; ++oc)
            acc[oc] = fmaf(wrow[kx * OC + oc], v[kx], acc[oc]);
        }
      }
    }
  }

  if constexpr (EPI == 1) {
    const float g0 = 1.f / (1.f + expf(-acc[20]));
    const float g1 = 1.f / (1.f + expf(-acc[21]));
    const float g2 = 1.f / (1.f + expf(-acc[22]));
    float o[20];
#pragma unroll
    for (int c = 0; c < 5; ++c) o[c] = fmaxf(acc[c], 0.f);
#pragma unroll
    for (int c = 0; c < 3; ++c) o[5 + c] = acc[5 + c] * g0;
#pragma unroll
    for (int c = 0; c < 5; ++c) o[8 + c] = acc[8 + c] * g1;
#pragma unroll
    for (int c = 0; c < 7; ++c) o[13 + c] = acc[13 + c] * g2;
    float* __restrict__ op = out + (size_t)b * 20 * NVOX + vox;
#pragma unroll
    for (int c = 0; c < 20; ++c) op[(size_t)c * NVOX] = o[c];
  } else if constexpr (EPI == 0) {
    float* __restrict__ op = out + ((size_t)(g * BATCH + b) * OC) * NVOX + vox;
#pragma unroll
    for (int oc = 0; oc < OC; ++oc) op[(size_t)oc * NVOX] = acc[oc];
  } else {
    float* __restrict__ op = out + (size_t)b * OC * NVOX + vox;
#pragma unroll
    for (int oc = 0; oc < OC; ++oc) op[(size_t)oc * NVOX] = acc[oc];
  }
}

// Sum ic-group partials (23 ch) + gating -> 20 ch output.
template <int G, int NVOX>
__global__ __launch_bounds__(THREADS)
void combine_gate_kernel(const float* __restrict__ P, float* __restrict__ out) {
  const int tid = blockIdx.x * THREADS + threadIdx.x;
  if (tid >= BATCH * NVOX) return;
  const int vox = tid % NVOX;
  const int b = tid / NVOX;
  float s[23];
#pragma unroll
  for (int oc = 0; oc < 23; ++oc) s[oc] = 0.f;
  for (int g = 0; g < G; ++g) {
    const float* __restrict__ p = P + ((size_t)(g * BATCH + b) * 23) * NVOX + vox;
#pragma unroll
    for (int oc = 0; oc < 23; ++oc) s[oc] += p[(size_t)oc * NVOX];
  }
  const float g0 = 1.f / (1.f + expf(-s[20]));
  const float g1 = 1.f / (1.f + expf(-s[21]));
  const float g2 = 1.f / (1.f + expf(-s[22]));
  float o[20];
#pragma unroll
  for (int c = 0; c < 5; ++c) o[c] = fmaxf(s[c], 0.f);
#pragma unroll
  for (int c = 0; c < 3; ++c) o[5 + c] = s[5 + c] * g0;
#pragma unroll
  for (int c = 0; c < 5; ++c) o[8 + c] = s[8 + c] * g1;
#pragma unroll
  for (int c = 0; c < 7; ++c) o[13 + c] = s[13 + c] * g2;
  float* __restrict__ op = out + (size_t)b * 20 * NVOX + vox;
#pragma unroll
  for (int c = 0; c < 20; ++c) op[(size_t)c * NVOX] = o[c];
}

// AvgSpacial over P2 partials [G][16][20][1000] + fc1(relu) + fc2.
template <int G>
__global__ __launch_bounds__(THREADS)
void head_kernel(const float* __restrict__ P2,
                 const float* __restrict__ fc1w, const float* __restrict__ fc1b,
                 const float* __restrict__ fc2w, const float* __restrict__ fc2b,
                 float* __restrict__ out) {
  const int b = blockIdx.x;
  const int t = threadIdx.x;
  __shared__ float part[200];
  __shared__ float xm[20];
  __shared__ float h[50];
  if (t < 200) {
    const int ch = t / 10, seg = t % 10;
    float s = 0.f;
    for (int g = 0; g < G; ++g) {
      const float* __restrict__ p = P2 + ((size_t)(g * BATCH + b) * 20 + ch) * 1000 + seg * 100;
      for (int i = 0; i < 100; ++i) s += p[i];
    }
    part[t] = s;
  }
  __syncthreads();
  if (t < 20) {
    float s = 0.f;
    for (int i = 0; i < 10; ++i) s += part[t * 10 + i];
    xm[t] = s * (1.0f / 1000.0f);
  }
  __syncthreads();
  if (t < 50) {
    float s = fc1b[t];
    for (int c = 0; c < 20; ++c) s += xm[c] * fc1w[t * 20 + c];
    h[t] = fmaxf(s, 0.f);
  }
  __syncthreads();
  if (t < 2) {
    float s = fc2b[t];
    for (int k = 0; k < 50; ++k) s += h[k] * fc2w[t * 50 + k];
    out[b * 2 + t] = s;
  }
}

extern "C" void kernel_launch(void* const* d_in, const int* in_sizes, int n_in,
                              void* d_out, int out_size, void* d_ws, size_t ws_size,
                              hipStream_t stream) {
  (void)in_sizes; (void)n_in; (void)out_size;
  const float* inp  = (const float*)d_in[0];
  const float* W0   = (const float*)d_in[1];
  const float* W1   = (const float*)d_in[2];
  const float* W2   = (const float*)d_in[3];
  const float* fc1w = (const float*)d_in[4];
  const float* fc1b = (const float*)d_in[5];
  const float* fc2w = (const float*)d_in[6];
  const float* fc2b = (const float*)d_in[7];
  float* out = (float*)d_out;

  float* ws = (float*)d_ws;
  float* K0 = ws;
  float* K1 = K0 + 2875;
  float* K2 = K1 + 57500;
  float* A0 = K2 + 50000;
  float* A1 = A0 + (size_t)11499840;
  float* X  = A1 + (size_t)1866240;  // variable region

  const size_t favail = ws_size / 4;
  const size_t base = 2875 + 57500 + 50000 + (size_t)11499840 + 1866240;  // 13,476,455
  const size_t p1_4 = (size_t)4 * BATCH * 23 * 5832;   // 8,584,704
  const size_t p1_2 = (size_t)2 * BATCH * 23 * 5832;   // 4,292,352
  const size_t p2sz = (size_t)10 * BATCH * 20 * 1000;  // 3,200,000

  hipLaunchKernelGGL(synth_kernel, dim3(1), dim3(256), 0, stream, W0, W1, W2, K0, K1, K2);

  // conv0: [16,1,64^3] -> gated -> A0 [16,20,33^3]
  {
    const int total = BATCH * 1 * 35937;
    hipLaunchKernelGGL((conv_kernel<1, 1, 23, 64, 33, 1>), dim3((total + THREADS - 1) / THREADS),
                       dim3(THREADS), 0, stream, inp, K0, A0);
  }

  if (favail >= base + p1_4 + p2sz) {
    float* P1 = X;
    float* P2 = X + p1_4;
    const int t1 = BATCH * 4 * 5832;
    hipLaunchKernelGGL((conv_kernel<20, 5, 23, 33, 18, 0>), dim3((t1 + THREADS - 1) / THREADS),
                       dim3(THREADS), 0, stream, A0, K1, P1);
    const int tc = BATCH * 5832;
    hipLaunchKernelGGL((combine_gate_kernel<4, 5832>), dim3((tc + THREADS - 1) / THREADS),
                       dim3(THREADS), 0, stream, P1, A1);
    const int t2 = BATCH * 10 * 1000;
    hipLaunchKernelGGL((conv_kernel<20, 2, 20, 18, 10, 0>), dim3((t2 + THREADS - 1) / THREADS),
                       dim3(THREADS), 0, stream, A1, K2, P2);
    hipLaunchKernelGGL((head_kernel<10>), dim3(BATCH), dim3(THREADS), 0, stream, P2, fc1w, fc1b,
                       fc2w, fc2b, out);
  } else if (favail >= base + p1_2 + p2sz) {
    float* P1 = X;
    float* P2 = X + p1_2;
    const int t1 = BATCH * 2 * 5832;
    hipLaunchKernelGGL((conv_kernel<20, 10, 23, 33, 18, 0>), dim3((t1 + THREADS - 1) / THREADS),
                       dim3(THREADS), 0, stream, A0, K1, P1);
    const int tc = BATCH * 5832;
    hipLaunchKernelGGL((combine_gate_kernel<2, 5832>), dim3((tc + THREADS - 1) / THREADS),
                       dim3(THREADS), 0, stream, P1, A1);
    const int t2 = BATCH * 10 * 1000;
    hipLaunchKernelGGL((conv_kernel<20, 2, 20, 18, 10, 0>), dim3((t2 + THREADS - 1) / THREADS),
                       dim3(THREADS), 0, stream, A1, K2, P2);
    hipLaunchKernelGGL((head_kernel<10>), dim3(BATCH), dim3(THREADS), 0, stream, P2, fc1w, fc1b,
                       fc2w, fc2b, out);
  } else {
    // fallback: fused, no partials (55 MB known-safe)
    float* A2 = X;
    const int t1 = BATCH * 5832;
    hipLaunchKernelGGL((conv_kernel<20, 20, 23, 33, 18, 1>), dim3((t1 + THREADS - 1) / THREADS),
                       dim3(THREADS), 0, stream, A0, K1, A1);
    const int t2 = BATCH * 1000;
    hipLaunchKernelGGL((conv_kernel<20, 20, 20, 18, 10, 2>), dim3((t2 + THREADS - 1) / THREADS),
                       dim3(THREADS), 0, stream, A1, K2, A2);
    hipLaunchKernelGGL((head_kernel<1>), dim3(BATCH), dim3(THREADS), 0, stream, A2, fc1w, fc1b,
                       fc2w, fc2b, out);
  }
}